// Round 3
// baseline (592.087 us; speedup 1.0000x reference)
//
#include <hip/hip_runtime.h>

// TransitionUp fused: segment mean-pool -> (tiny MLP, replicated per block)
// -> [x,h[seg]]@W1+BN+ReLU, all in ONE kernel with a device-scope grid
// barrier (co-residency guaranteed: 512 blocks, __launch_bounds__(256,2)).
//
// Folded math:
//   a[j]     = gamma[j] * rsqrt(run_var[j]+eps)
//   bias'[b][j] = (relu(mean_b@W2+b2) @ W1[64:] + b1)[j]*a[j] + beta[j]-mean...
//   out[p][j] = relu( x[p] @ (W1[:64]*a)[:,j] + bias'[seg(p)][j] )
//
// R3 changes vs R2: single fused kernel (was 3 + memset); x re-read in the
// compute phase hits L3 (warmed by the pool phase, x = 256 MB = L3 size);
// out written with nontemporal stores so the write stream doesn't evict x.

#define MAXB 16
#define NBLK 512   // 2 blocks/CU x 256 CUs -> all co-resident (barrier-safe)

typedef _Float16 half8 __attribute__((ext_vector_type(8)));
typedef float float4v __attribute__((ext_vector_type(4)));

__global__ __launch_bounds__(256, 2) void fused_kernel(
    const float* __restrict__ x, const int* __restrict__ o,
    const float* __restrict__ W2, const float* __restrict__ b2,
    const float* __restrict__ W1, const float* __restrict__ b1,
    const float* __restrict__ gamma, const float* __restrict__ beta,
    const float* __restrict__ rmean, const float* __restrict__ rvar,
    float* __restrict__ gsums, unsigned* __restrict__ bar,
    float* __restrict__ out, int nB, int npts) {
  __shared__ int so_s[MAXB];
  __shared__ float red[16 * 64];      // phase A reduce / phase B mean
  __shared__ float sh[MAXB * 64];     // phase A slow bins / phase B h
  __shared__ float sbias[MAXB * 64];  // folded per-segment bias

  const int tid = threadIdx.x;
  const int ptsPerBlock = npts / NBLK;            // 2048 at N=1M
  const int p0 = blockIdx.x * ptsPerBlock;

  if (tid < nB) so_s[tid] = o[tid];
  __syncthreads();

  // ---------------- phase A: segment column sums ----------------
  const int c4 = (tid & 15) * 4;
  const int r  = tid >> 4;
  const int iters = ptsPerBlock >> 4;

  int sFirst = 0;
  while (p0 >= so_s[sFirst]) sFirst++;
  int sLast = sFirst;
  while (p0 + ptsPerBlock - 1 >= so_s[sLast]) sLast++;

  if (sFirst == sLast) {  // block entirely inside one segment (common)
    float a0 = 0.f, a1 = 0.f, a2 = 0.f, a3 = 0.f;
    const float* xp = x + (size_t)(p0 + r) * 64 + c4;
#pragma unroll 4
    for (int i = 0; i < iters; ++i) {
      float4 v = *(const float4*)(xp + (size_t)i * 1024);
      a0 += v.x; a1 += v.y; a2 += v.z; a3 += v.w;
    }
    float4 t = {a0, a1, a2, a3};
    *(float4*)&red[r * 64 + c4] = t;
    __syncthreads();
    if (tid < 64) {
      float s = 0.f;
#pragma unroll
      for (int rr = 0; rr < 16; ++rr) s += red[rr * 64 + tid];
      atomicAdd(&gsums[sFirst * 64 + tid], s);
    }
  } else {  // boundary block (rare): per-point binning into LDS
    for (int i = tid; i < nB * 64; i += 256) sh[i] = 0.f;
    __syncthreads();
    for (int i = 0; i < iters; ++i) {
      int p = p0 + i * 16 + r;
      int s = 0;
      while (p >= so_s[s]) s++;
      float4 v = *(const float4*)(x + (size_t)p * 64 + c4);
      atomicAdd(&sh[s * 64 + c4 + 0], v.x);
      atomicAdd(&sh[s * 64 + c4 + 1], v.y);
      atomicAdd(&sh[s * 64 + c4 + 2], v.z);
      atomicAdd(&sh[s * 64 + c4 + 3], v.w);
    }
    __syncthreads();
    for (int i = tid; i < nB * 64; i += 256) {
      float v = sh[i];
      if (v != 0.f) atomicAdd(&gsums[i], v);
    }
    __syncthreads();  // sh reused in phase B
  }

  // ----- B-fragment build (independent of pooling: overlap the barrier) ----
  const int lane = tid & 63;
  const int m    = lane & 15;
  const int quad = lane >> 4;
  half8 bfrag[4][2];
#pragma unroll
  for (int t = 0; t < 4; ++t) {
    const int jj = t * 16 + m;
    const float at = gamma[jj] * rsqrtf(rvar[jj] + 1e-5f);
#pragma unroll
    for (int h = 0; h < 2; ++h)
#pragma unroll
      for (int i2 = 0; i2 < 8; ++i2)
        bfrag[t][h][i2] = (_Float16)(W1[(h * 32 + quad * 8 + i2) * 64 + jj] * at);
  }

  // ---------------- grid barrier (single-use, bar zeroed by memset) -------
  __threadfence();
  __syncthreads();
  if (tid == 0) {
    __hip_atomic_fetch_add(bar, 1u, __ATOMIC_ACQ_REL, __HIP_MEMORY_SCOPE_AGENT);
    while (__hip_atomic_load(bar, __ATOMIC_ACQUIRE, __HIP_MEMORY_SCOPE_AGENT) <
           (unsigned)NBLK)
      __builtin_amdgcn_s_sleep(1);
  }
  __syncthreads();

  // ---------------- phase B: replicated tiny MLP -> sbias ----------------
  const int j  = tid & 63;
  const int bq = tid >> 6;
  for (int i = tid; i < nB * 64; i += 256) {
    int b = i >> 6;
    int cnt = so_s[b] - (b ? so_s[b - 1] : 0);
    float g = __hip_atomic_load(&gsums[i], __ATOMIC_RELAXED,
                                __HIP_MEMORY_SCOPE_AGENT);
    red[i] = g / (float)cnt;  // mean
  }
  __syncthreads();

  for (int b = bq; b < nB; b += 4) {
    float q0 = 0.f, q1 = 0.f, q2 = 0.f, q3 = 0.f;
#pragma unroll
    for (int c = 0; c < 64; c += 4) {
      q0 = fmaf(red[b * 64 + c + 0], W2[(c + 0) * 64 + j], q0);
      q1 = fmaf(red[b * 64 + c + 1], W2[(c + 1) * 64 + j], q1);
      q2 = fmaf(red[b * 64 + c + 2], W2[(c + 2) * 64 + j], q2);
      q3 = fmaf(red[b * 64 + c + 3], W2[(c + 3) * 64 + j], q3);
    }
    sh[b * 64 + j] = fmaxf(((q0 + q1) + (q2 + q3)) + b2[j], 0.f);
  }
  __syncthreads();

  {
    const float aj = gamma[j] * rsqrtf(rvar[j] + 1e-5f);
    const float dj = beta[j] - rmean[j] * aj;
    for (int b = bq; b < nB; b += 4) {
      float q0 = 0.f, q1 = 0.f, q2 = 0.f, q3 = 0.f;
#pragma unroll
      for (int c = 0; c < 64; c += 4) {
        q0 = fmaf(sh[b * 64 + c + 0], W1[(64 + c + 0) * 64 + j], q0);
        q1 = fmaf(sh[b * 64 + c + 1], W1[(64 + c + 1) * 64 + j], q1);
        q2 = fmaf(sh[b * 64 + c + 2], W1[(64 + c + 2) * 64 + j], q2);
        q3 = fmaf(sh[b * 64 + c + 3], W1[(64 + c + 3) * 64 + j], q3);
      }
      sbias[b * 64 + j] = (((q0 + q1) + (q2 + q3)) + b1[j]) * aj + dj;
    }
  }
  __syncthreads();

  // ---------------- phase C: out = relu(x@W' + bias'[seg]) ---------------
  const int ov = (m < nB) ? so_s[m] : 0x7fffffff;
  const int w = tid >> 6;
  const int wrows = ptsPerBlock >> 2;   // rows per wave (512)
  const int rows0 = p0 + w * wrows;
  const int ntiles = wrows >> 4;        // 16-row tiles per wave (32)

  float4 f0, f1, f2, f3;
  {
    const float* p = x + (size_t)(rows0 + m) * 64 + quad * 8;
    f0 = *(const float4*)(p + 0);
    f1 = *(const float4*)(p + 4);
    f2 = *(const float4*)(p + 32);
    f3 = *(const float4*)(p + 36);
  }

  for (int i = 0; i < ntiles; ++i) {
    const int row0 = rows0 + i * 16;
    half8 a0, a1;
    a0[0] = (_Float16)f0.x; a0[1] = (_Float16)f0.y;
    a0[2] = (_Float16)f0.z; a0[3] = (_Float16)f0.w;
    a0[4] = (_Float16)f1.x; a0[5] = (_Float16)f1.y;
    a0[6] = (_Float16)f1.z; a0[7] = (_Float16)f1.w;
    a1[0] = (_Float16)f2.x; a1[1] = (_Float16)f2.y;
    a1[2] = (_Float16)f2.z; a1[3] = (_Float16)f2.w;
    a1[4] = (_Float16)f3.x; a1[5] = (_Float16)f3.y;
    a1[6] = (_Float16)f3.z; a1[7] = (_Float16)f3.w;

    if (i < ntiles - 1) {  // prefetch next tile (L3-hot after phase A)
      const float* p = x + (size_t)(row0 + 16 + m) * 64 + quad * 8;
      f0 = *(const float4*)(p + 0);
      f1 = *(const float4*)(p + 4);
      f2 = *(const float4*)(p + 32);
      f3 = *(const float4*)(p + 36);
    }

    const int s0 = (int)__popcll(__ballot(row0 >= ov) & 0xFFFFull);
    const int s1 = (int)__popcll(__ballot(row0 + 15 >= ov) & 0xFFFFull);

    if (s0 == s1) {  // tile in one segment (common)
#pragma unroll
      for (int t = 0; t < 4; ++t) {
        float4v c = {0.f, 0.f, 0.f, 0.f};
        c = __builtin_amdgcn_mfma_f32_16x16x32_f16(a0, bfrag[t][0], c, 0, 0, 0);
        c = __builtin_amdgcn_mfma_f32_16x16x32_f16(a1, bfrag[t][1], c, 0, 0, 0);
        const float bv = sbias[s0 * 64 + t * 16 + m];
        float* op = out + (size_t)(row0 + quad * 4) * 64 + t * 16 + m;
#pragma unroll
        for (int rg = 0; rg < 4; ++rg)
          __builtin_nontemporal_store(fmaxf(c[rg] + bv, 0.f),
                                      op + (size_t)rg * 64);
      }
    } else {  // boundary tile (rare)
#pragma unroll
      for (int t = 0; t < 4; ++t) {
        float4v c = {0.f, 0.f, 0.f, 0.f};
        c = __builtin_amdgcn_mfma_f32_16x16x32_f16(a0, bfrag[t][0], c, 0, 0, 0);
        c = __builtin_amdgcn_mfma_f32_16x16x32_f16(a1, bfrag[t][1], c, 0, 0, 0);
#pragma unroll
        for (int rg = 0; rg < 4; ++rg) {
          const int row = row0 + quad * 4 + rg;
          int s = 0;
          for (int q2 = 0; q2 < nB; ++q2) s += (row >= so_s[q2]) ? 1 : 0;
          const float bv = sbias[s * 64 + t * 16 + m];
          __builtin_nontemporal_store(fmaxf(c[rg] + bv, 0.f),
                                      out + (size_t)row * 64 + t * 16 + m);
        }
      }
    }
  }
}

// ---------------------------------------------------------------- launch
extern "C" void kernel_launch(void* const* d_in, const int* in_sizes, int n_in,
                              void* d_out, int out_size, void* d_ws, size_t ws_size,
                              hipStream_t stream) {
  const float* x     = (const float*)d_in[0];
  const int*   o     = (const int*)d_in[1];
  const float* W2    = (const float*)d_in[2];
  const float* b2    = (const float*)d_in[3];
  const float* W1    = (const float*)d_in[4];
  const float* b1    = (const float*)d_in[5];
  const float* gamma = (const float*)d_in[6];
  const float* beta  = (const float*)d_in[7];
  const float* rmean = (const float*)d_in[8];
  const float* rvar  = (const float*)d_in[9];
  float* out = (float*)d_out;

  const int npts = in_sizes[0] / 64;
  const int nB   = in_sizes[1];

  float*    gsums = (float*)d_ws;                    // [16*64] f32
  unsigned* bar   = (unsigned*)(gsums + MAXB * 64);  // barrier counter

  // zero gsums + barrier in one memset (the only extra dispatch)
  hipMemsetAsync(d_ws, 0, MAXB * 64 * sizeof(float) + 64, stream);

  fused_kernel<<<NBLK, 256, 0, stream>>>(x, o, W2, b2, W1, b1, gamma, beta,
                                         rmean, rvar, gsums, bar, out, nB, npts);
}

// Round 4
// 527.980 us; speedup vs baseline: 1.1214x; 1.1214x over previous
//
#include <hip/hip_runtime.h>

// TransitionUp: segment mean-pool -> linear2+ReLU (tiny) -> broadcast ->
// [x, h[seg]] @ W1 + b1 -> BN(eval) -> ReLU.
//
// Folded math:
//   a[j]     = gamma[j] * rsqrt(run_var[j]+eps)
//   d[j]     = beta[j] - run_mean[j]*a[j]
//   W'[k][j] = W1[k][j] * a[j]                  (k in 0..63, the x-half)
//   bias'[b][j] = (h[b]@W1[64:] + b1)[j]*a[j] + d[j]
//   out[p][j] = relu( x[p]@W'[:,j] + bias'[seg(p)][j] )
//
// R4 = R2 split structure (fused+grid-barrier R3 regressed: 2 blk/CU occupancy
// cap left all pipes idle) + NT stores for out (R3 proved L3 keeps x across
// the pool->main gap: FETCH 262MB not 512MB) + bias' staged in LDS + pool
// unroll 8. main kernel: MFMA f16 16x16x32, no LDS in hot loop, B-matrix
// pinned in 32 VGPRs, C layout col=lane&15,row=quad*4+reg (m89-verified).

#define MAXB 16

typedef _Float16 half8 __attribute__((ext_vector_type(8)));
typedef float float4v __attribute__((ext_vector_type(4)));

// ---------------------------------------------------------------- kernel 1
// Per-segment column sums of x into gsums[B][64] (pre-zeroed via memset).
__global__ __launch_bounds__(256) void pool_kernel(
    const float* __restrict__ x, const int* __restrict__ o,
    float* __restrict__ gsums, int nB, int ptsPerBlock) {
  __shared__ int so_s[MAXB];
  __shared__ float red[16 * 64];      // fast-path reduction scratch
  __shared__ float ssum2[MAXB * 64];  // slow-path bins
  const int tid = threadIdx.x;
  if (tid < nB) so_s[tid] = o[tid];
  __syncthreads();

  const int c4 = (tid & 15) * 4;  // 4 consecutive columns per thread
  const int r  = tid >> 4;        // 16 rows per 256 threads
  const int p0 = blockIdx.x * ptsPerBlock;
  const int iters = ptsPerBlock >> 4;

  int sFirst = 0;
  while (p0 >= so_s[sFirst]) sFirst++;
  int sLast = sFirst;
  while (p0 + ptsPerBlock - 1 >= so_s[sLast]) sLast++;

  if (sFirst == sLast) {  // block entirely in one segment (common)
    float a0 = 0.f, a1 = 0.f, a2 = 0.f, a3 = 0.f;
    const float* xp = x + (size_t)(p0 + r) * 64 + c4;
#pragma unroll 8
    for (int i = 0; i < iters; ++i) {
      float4 v = *(const float4*)(xp + (size_t)i * 1024);
      a0 += v.x; a1 += v.y; a2 += v.z; a3 += v.w;
    }
    float4 t = {a0, a1, a2, a3};
    *(float4*)&red[r * 64 + c4] = t;
    __syncthreads();
    if (tid < 64) {
      float s = 0.f;
#pragma unroll
      for (int rr = 0; rr < 16; ++rr) s += red[rr * 64 + tid];
      atomicAdd(&gsums[sFirst * 64 + tid], s);
    }
  } else {  // boundary block (rare): per-point binning
    for (int i = tid; i < nB * 64; i += 256) ssum2[i] = 0.f;
    __syncthreads();
    for (int i = 0; i < iters; ++i) {
      int p = p0 + i * 16 + r;
      int s = 0;
      while (p >= so_s[s]) s++;
      float4 v = *(const float4*)(x + (size_t)p * 64 + c4);
      atomicAdd(&ssum2[s * 64 + c4 + 0], v.x);
      atomicAdd(&ssum2[s * 64 + c4 + 1], v.y);
      atomicAdd(&ssum2[s * 64 + c4 + 2], v.z);
      atomicAdd(&ssum2[s * 64 + c4 + 3], v.w);
    }
    __syncthreads();
    for (int i = tid; i < nB * 64; i += 256) {
      float v = ssum2[i];
      if (v != 0.f) atomicAdd(&gsums[i], v);
    }
  }
}

// ---------------------------------------------------------------- kernel 2
// mean -> h = relu(mean@W2+b2) -> bias'[b][j]; WpT[j][k] = f16(W1[k][j]*a[j]).
__global__ __launch_bounds__(256) void mid_kernel(
    const float* __restrict__ gsums, const int* __restrict__ o,
    const float* __restrict__ W2, const float* __restrict__ b2,
    const float* __restrict__ W1, const float* __restrict__ b1,
    const float* __restrict__ gamma, const float* __restrict__ beta,
    const float* __restrict__ rmean, const float* __restrict__ rvar,
    float* __restrict__ biasp, _Float16* __restrict__ WpT, int nB) {
  __shared__ float smean[MAXB * 64];
  __shared__ float sh[MAXB * 64];
  const int tid = threadIdx.x;
  const int j = tid & 63;
  const int bq = tid >> 6;

  for (int i = tid; i < nB * 64; i += 256) {
    int b = i >> 6;
    int cnt = o[b] - (b ? o[b - 1] : 0);
    smean[i] = gsums[i] / (float)cnt;
  }
  __syncthreads();

  for (int b = bq; b < nB; b += 4) {
    float p0 = 0.f, p1 = 0.f, p2 = 0.f, p3 = 0.f;  // 4 chains for ILP
#pragma unroll
    for (int c = 0; c < 64; c += 4) {
      p0 = fmaf(smean[b * 64 + c + 0], W2[(c + 0) * 64 + j], p0);
      p1 = fmaf(smean[b * 64 + c + 1], W2[(c + 1) * 64 + j], p1);
      p2 = fmaf(smean[b * 64 + c + 2], W2[(c + 2) * 64 + j], p2);
      p3 = fmaf(smean[b * 64 + c + 3], W2[(c + 3) * 64 + j], p3);
    }
    sh[b * 64 + j] = fmaxf(((p0 + p1) + (p2 + p3)) + b2[j], 0.f);
  }
  __syncthreads();

  const float a = gamma[j] * rsqrtf(rvar[j] + 1e-5f);
  const float d = beta[j] - rmean[j] * a;
  for (int b = bq; b < nB; b += 4) {
    float p0 = 0.f, p1 = 0.f, p2 = 0.f, p3 = 0.f;
#pragma unroll
    for (int c = 0; c < 64; c += 4) {
      p0 = fmaf(sh[b * 64 + c + 0], W1[(64 + c + 0) * 64 + j], p0);
      p1 = fmaf(sh[b * 64 + c + 1], W1[(64 + c + 1) * 64 + j], p1);
      p2 = fmaf(sh[b * 64 + c + 2], W1[(64 + c + 2) * 64 + j], p2);
      p3 = fmaf(sh[b * 64 + c + 3], W1[(64 + c + 3) * 64 + j], p3);
    }
    biasp[b * 64 + j] = (((p0 + p1) + (p2 + p3)) + b1[j]) * a + d;
  }
  for (int k = bq * 16; k < bq * 16 + 16; ++k)
    WpT[j * 64 + k] = (_Float16)(W1[k * 64 + j] * a);
}

// ---------------------------------------------------------------- kernel 3
// Each wave: 8 row-tiles of 16 points, 4 col-tiles of 16. No LDS in hot loop.
// A frag (m89 layout): lane holds A[m=lane&15][k=quad*8+j], fp32->f16 cvt.
// B frag: lane holds B[k=quad*8+j][n=lane&15] from WpT[n][k] (contiguous).
// out written with NT stores so the write stream doesn't evict L3-hot x.
__global__ __launch_bounds__(256) void main_kernel(
    const float* __restrict__ x, const int* __restrict__ o,
    const _Float16* __restrict__ WpT, const float* __restrict__ biasp,
    float* __restrict__ out, int nB) {
  __shared__ float sbias[MAXB * 64];
  const int tid  = threadIdx.x;
  const int lane = tid & 63;
  const int m = lane & 15;
  const int quad = lane >> 4;
  const int rows0 = (blockIdx.x * 4 + (tid >> 6)) * 128;

  // stage folded bias in LDS (reads are quad-broadcast -> conflict-free)
  *(float4*)&sbias[tid * 4] = *(const float4*)(biasp + tid * 4);

  // B = W' pinned in registers: 4 col-tiles x 2 K-halves x 8 f16
  half8 bfrag[4][2];
#pragma unroll
  for (int t = 0; t < 4; ++t)
#pragma unroll
    for (int h = 0; h < 2; ++h)
      bfrag[t][h] = *(const half8*)(WpT + (t * 16 + m) * 64 + h * 32 + quad * 8);

  // lane m holds o[m] for ballot-based segment lookup
  const int ov = (m < nB) ? o[m] : 0x7fffffff;

  float4 f0, f1, f2, f3;  // fp32 staging for one 16x64 A-tile
  {
    const float* p = x + (size_t)(rows0 + m) * 64 + quad * 8;
    f0 = *(const float4*)(p + 0);
    f1 = *(const float4*)(p + 4);
    f2 = *(const float4*)(p + 32);
    f3 = *(const float4*)(p + 36);
  }
  __syncthreads();

  for (int i = 0; i < 8; ++i) {
    const int row0 = rows0 + i * 16;
    half8 a0, a1;
    a0[0] = (_Float16)f0.x; a0[1] = (_Float16)f0.y;
    a0[2] = (_Float16)f0.z; a0[3] = (_Float16)f0.w;
    a0[4] = (_Float16)f1.x; a0[5] = (_Float16)f1.y;
    a0[6] = (_Float16)f1.z; a0[7] = (_Float16)f1.w;
    a1[0] = (_Float16)f2.x; a1[1] = (_Float16)f2.y;
    a1[2] = (_Float16)f2.z; a1[3] = (_Float16)f2.w;
    a1[4] = (_Float16)f3.x; a1[5] = (_Float16)f3.y;
    a1[6] = (_Float16)f3.z; a1[7] = (_Float16)f3.w;

    if (i < 7) {  // prefetch next tile while MFMA+stores run (L3-hot)
      const float* p = x + (size_t)(row0 + 16 + m) * 64 + quad * 8;
      f0 = *(const float4*)(p + 0);
      f1 = *(const float4*)(p + 4);
      f2 = *(const float4*)(p + 32);
      f3 = *(const float4*)(p + 36);
    }

    // segment of this 16-row tile via ballot popcount (o in lanes 0..15)
    const int s0 = (int)__popcll(__ballot(row0 >= ov) & 0xFFFFull);
    const int s1 = (int)__popcll(__ballot(row0 + 15 >= ov) & 0xFFFFull);

    if (s0 == s1) {  // tile entirely in one segment (common)
#pragma unroll
      for (int t = 0; t < 4; ++t) {
        float4v c = {0.f, 0.f, 0.f, 0.f};
        c = __builtin_amdgcn_mfma_f32_16x16x32_f16(a0, bfrag[t][0], c, 0, 0, 0);
        c = __builtin_amdgcn_mfma_f32_16x16x32_f16(a1, bfrag[t][1], c, 0, 0, 0);
        const float bv = sbias[s0 * 64 + t * 16 + m];
        float* op = out + (size_t)(row0 + quad * 4) * 64 + t * 16 + m;
#pragma unroll
        for (int rg = 0; rg < 4; ++rg)
          __builtin_nontemporal_store(fmaxf(c[rg] + bv, 0.f),
                                      op + (size_t)rg * 64);
      }
    } else {  // boundary tile (rare): per-row segment scan
#pragma unroll
      for (int t = 0; t < 4; ++t) {
        float4v c = {0.f, 0.f, 0.f, 0.f};
        c = __builtin_amdgcn_mfma_f32_16x16x32_f16(a0, bfrag[t][0], c, 0, 0, 0);
        c = __builtin_amdgcn_mfma_f32_16x16x32_f16(a1, bfrag[t][1], c, 0, 0, 0);
#pragma unroll
        for (int rg = 0; rg < 4; ++rg) {
          const int row = row0 + quad * 4 + rg;
          int s = 0;
          for (int q2 = 0; q2 < nB; ++q2) s += (row >= o[q2]) ? 1 : 0;
          const float bv = sbias[s * 64 + t * 16 + m];
          __builtin_nontemporal_store(fmaxf(c[rg] + bv, 0.f),
                                      out + (size_t)row * 64 + t * 16 + m);
        }
      }
    }
  }
}

// ---------------------------------------------------------------- launch
extern "C" void kernel_launch(void* const* d_in, const int* in_sizes, int n_in,
                              void* d_out, int out_size, void* d_ws, size_t ws_size,
                              hipStream_t stream) {
  const float* x     = (const float*)d_in[0];
  const int*   o     = (const int*)d_in[1];
  const float* W2    = (const float*)d_in[2];
  const float* b2    = (const float*)d_in[3];
  const float* W1    = (const float*)d_in[4];
  const float* b1    = (const float*)d_in[5];
  const float* gamma = (const float*)d_in[6];
  const float* beta  = (const float*)d_in[7];
  const float* rmean = (const float*)d_in[8];
  const float* rvar  = (const float*)d_in[9];
  float* out = (float*)d_out;

  const int npts = in_sizes[0] / 64;
  const int nB   = in_sizes[1];

  float*    gsums = (float*)d_ws;                    // [16*64] f32
  float*    biasp = gsums + MAXB * 64;               // [16*64] f32
  _Float16* WpT   = (_Float16*)(biasp + MAXB * 64);  // [64*64] f16

  hipMemsetAsync(gsums, 0, MAXB * 64 * sizeof(float), stream);

  const int blocks1 = 2048;                          // 512 pts/block at N=1M
  pool_kernel<<<blocks1, 256, 0, stream>>>(x, o, gsums, nB, npts / blocks1);
  mid_kernel<<<1, 256, 0, stream>>>(gsums, o, W2, b2, W1, b1, gamma, beta,
                                    rmean, rvar, biasp, WpT, nB);
  main_kernel<<<npts / 512, 256, 0, stream>>>(x, o, WpT, biasp, out, nB);
}